// Round 2
// baseline (721.113 us; speedup 1.0000x reference)
//
#include <hip/hip_runtime.h>
#include <hip/hip_cooperative_groups.h>
#include <math.h>

namespace cg = cooperative_groups;

#define N_ROWS 131072
#define D_COLS 512
#define TOTAL4 (N_ROWS * D_COLS / 4)   // 16777216 float4 elements

typedef float v4f __attribute__((ext_vector_type(4)));

// ---------------- Fused cooperative kernel ----------------
// 1024 blocks x 256 threads, all co-resident (4 blocks/CU, 16 waves/CU).
// Phase 1: per-block sum/sumsq partials (X: 256 MiB HBM read).
// Phase 2: 128 blocks reduce the 4 MiB of partials -> scale/bias.
// Phase 3: Y = X*scale + bias; X is L3-warm from phase 1 (X == 256 MiB == L3),
//          Y uses non-temporal stores so it doesn't evict X mid-phase.
#define FUSED_NBLK    1024
#define FUSED_THREADS 256
#define FUSED_STRIDE  (FUSED_NBLK * FUSED_THREADS)   // 262144 float4s (mult of 128)
#define FUSED_ITERS   (TOTAL4 / FUSED_STRIDE)        // 64, exact

__global__ __launch_bounds__(FUSED_THREADS, 4)
void bn_fused_kernel(const v4f* __restrict__ X,
                     v4f* __restrict__ Y,
                     const float* __restrict__ gamma,
                     const float* __restrict__ beta,
                     float* __restrict__ partial,   // FUSED_NBLK * 1024 floats
                     float* __restrict__ sb) {      // scale[512] bias[512]
    cg::grid_group grid = cg::this_grid();
    const int t = threadIdx.x;
    const int g = blockIdx.x * FUSED_THREADS + t;

    __shared__ v4f ls[FUSED_THREADS];
    __shared__ v4f lq[FUSED_THREADS];

    // ---- Phase 1: partial sum / sumsq (column quad loop-invariant) ----
    v4f s = (v4f)0.0f, q = (v4f)0.0f;
    #pragma unroll 8
    for (int k = 0; k < FUSED_ITERS; ++k) {
        v4f x = X[g + k * FUSED_STRIDE];
        s += x;
        q += x * x;
    }
    ls[t] = s; lq[t] = q;
    __syncthreads();
    if (t < 128) {   // t and t+128 own the same column quad
        v4f sv = ls[t] + ls[t + 128];
        v4f qv = lq[t] + lq[t + 128];
        float* dst = partial + (size_t)blockIdx.x * 1024;
        *(v4f*)(dst + 4 * t)       = sv;
        *(v4f*)(dst + 512 + 4 * t) = qv;
    }
    grid.sync();

    // ---- Phase 2: 128 blocks, one per column quad ----
    if (blockIdx.x < 128) {
        const int qd = blockIdx.x;
        v4f s2 = (v4f)0.0f, q2 = (v4f)0.0f;
        for (int b = t; b < FUSED_NBLK; b += FUSED_THREADS) {
            const float* src = partial + (size_t)b * 1024;
            s2 += *(const v4f*)(src + 4 * qd);
            q2 += *(const v4f*)(src + 512 + 4 * qd);
        }
        ls[t] = s2; lq[t] = q2;
        __syncthreads();
        for (int off = 128; off > 0; off >>= 1) {
            if (t < off) { ls[t] += ls[t + off]; lq[t] += lq[t + off]; }
            __syncthreads();
        }
        if (t == 0) {
            const float invN = 1.0f / (float)N_ROWS;
            v4f sv = ls[0], qv = lq[0];
            v4f mean = sv * invN;
            v4f var  = qv * invN - mean * mean;   // no epsilon, per reference
            v4f inv;
            inv.x = rsqrtf(var.x); inv.y = rsqrtf(var.y);
            inv.z = rsqrtf(var.z); inv.w = rsqrtf(var.w);
            v4f g4 = *(const v4f*)(gamma + 4 * qd);
            v4f b4 = *(const v4f*)(beta  + 4 * qd);
            v4f sc = g4 * inv;
            v4f bi = b4 - mean * sc;
            *(v4f*)(sb + 4 * qd)       = sc;
            *(v4f*)(sb + 512 + 4 * qd) = bi;
        }
    }
    grid.sync();

    // ---- Phase 3: normalize (X re-read is L3-warm) ----
    const int c = (g & 127) * 4;
    const v4f sc = *(const v4f*)(sb + c);
    const v4f bi = *(const v4f*)(sb + 512 + c);
    #pragma unroll 8
    for (int k = 0; k < FUSED_ITERS; ++k) {
        v4f x = X[g + k * FUSED_STRIDE];
        __builtin_nontemporal_store(x * sc + bi, &Y[g + k * FUSED_STRIDE]);
    }
}

// ---------------- Fallback 3-kernel path (if ws too small) ----------------
template<int NBLK>
__global__ __launch_bounds__(256)
void bn_stats_kernel(const v4f* __restrict__ X, float* __restrict__ partial) {
    constexpr int STRIDE = NBLK * 256;
    constexpr int ITERS  = TOTAL4 / STRIDE;
    const int t = threadIdx.x;
    const int g = blockIdx.x * 256 + t;
    v4f s = (v4f)0.0f, q = (v4f)0.0f;
    #pragma unroll 8
    for (int k = 0; k < ITERS; ++k) {
        v4f x = X[g + k * STRIDE];
        s += x; q += x * x;
    }
    __shared__ v4f ls[256];
    __shared__ v4f lq[256];
    ls[t] = s; lq[t] = q;
    __syncthreads();
    if (t < 128) {
        v4f sv = ls[t] + ls[t + 128];
        v4f qv = lq[t] + lq[t + 128];
        float* dst = partial + (size_t)blockIdx.x * 1024;
        *(v4f*)(dst + 4 * t)       = sv;
        *(v4f*)(dst + 512 + 4 * t) = qv;
    }
}

__global__ __launch_bounds__(256)
void bn_finalize_kernel(const float* __restrict__ partial,
                        const float* __restrict__ gamma,
                        const float* __restrict__ beta,
                        float* __restrict__ sb, int B) {
    const int qd = blockIdx.x;
    const int t  = threadIdx.x;
    v4f s = (v4f)0.0f, q = (v4f)0.0f;
    for (int b = t; b < B; b += 256) {
        const float* src = partial + (size_t)b * 1024;
        s += *(const v4f*)(src + 4 * qd);
        q += *(const v4f*)(src + 512 + 4 * qd);
    }
    __shared__ v4f ls[256];
    __shared__ v4f lq[256];
    ls[t] = s; lq[t] = q;
    __syncthreads();
    for (int off = 128; off > 0; off >>= 1) {
        if (t < off) { ls[t] += ls[t + off]; lq[t] += lq[t + off]; }
        __syncthreads();
    }
    if (t == 0) {
        const float invN = 1.0f / (float)N_ROWS;
        v4f sv = ls[0], qv = lq[0];
        v4f mean = sv * invN;
        v4f var  = qv * invN - mean * mean;
        v4f inv;
        inv.x = rsqrtf(var.x); inv.y = rsqrtf(var.y);
        inv.z = rsqrtf(var.z); inv.w = rsqrtf(var.w);
        v4f g4 = *(const v4f*)(gamma + 4 * qd);
        v4f b4 = *(const v4f*)(beta  + 4 * qd);
        v4f sc = g4 * inv;
        v4f bi = b4 - mean * sc;
        *(v4f*)(sb + 4 * qd)       = sc;
        *(v4f*)(sb + 512 + 4 * qd) = bi;
    }
}

template<int NBLK>
__global__ __launch_bounds__(256)
void bn_norm_kernel(const v4f* __restrict__ X, v4f* __restrict__ Y,
                    const float* __restrict__ sb) {
    constexpr int STRIDE = NBLK * 256;
    constexpr int ITERS  = TOTAL4 / STRIDE;
    const int g = blockIdx.x * 256 + threadIdx.x;
    const int c = (g & 127) * 4;
    const v4f sc = *(const v4f*)(sb + c);
    const v4f bi = *(const v4f*)(sb + 512 + c);
    #pragma unroll 4
    for (int k = 0; k < ITERS; ++k) {
        v4f x = X[g + k * STRIDE];
        __builtin_nontemporal_store(x * sc + bi, &Y[g + k * STRIDE]);
    }
}

extern "C" void kernel_launch(void* const* d_in, const int* in_sizes, int n_in,
                              void* d_out, int out_size, void* d_ws, size_t ws_size,
                              hipStream_t stream) {
    const float* X     = (const float*)d_in[0];
    const float* gamma = (const float*)d_in[1];
    const float* beta  = (const float*)d_in[2];
    float* Y  = (float*)d_out;
    float* ws = (float*)d_ws;

    const size_t fused_need = ((size_t)FUSED_NBLK * 1024 + 1024) * sizeof(float);
    if (ws_size >= fused_need) {
        float* partial = ws;
        float* sb      = ws + (size_t)FUSED_NBLK * 1024;
        const v4f* X4 = (const v4f*)X;
        v4f* Y4 = (v4f*)Y;
        void* args[] = { (void*)&X4, (void*)&Y4, (void*)&gamma, (void*)&beta,
                         (void*)&partial, (void*)&sb };
        hipLaunchCooperativeKernel((const void*)bn_fused_kernel,
                                   dim3(FUSED_NBLK), dim3(FUSED_THREADS),
                                   args, 0, stream);
    } else {
        int B = 512;
        while (B > 64 && ((size_t)B * 1024 + 1024) * sizeof(float) > ws_size) B >>= 1;
        float* partial = ws;
        float* sb      = ws + (size_t)B * 1024;
        bn_stats_kernel<512><<<512, 256, 0, stream>>>((const v4f*)X, partial);
        bn_finalize_kernel<<<128, 256, 0, stream>>>(partial, gamma, beta, sb, B);
        bn_norm_kernel<4096><<<4096, 256, 0, stream>>>((const v4f*)X, (v4f*)Y, sb);
    }
}

// Round 3
// 494.649 us; speedup vs baseline: 1.4578x; 1.4578x over previous
//
#include <hip/hip_runtime.h>
#include <math.h>

#define N_ROWS 131072
#define D_COLS 512
#define TOTAL4 (N_ROWS * D_COLS / 4)   // 16777216 float4 elements

typedef float v4f __attribute__((ext_vector_type(4)));

// ---------------- Pass 1: per-block sum/sumsq partials ----------------
// 1024 blocks x 512 threads (8192 waves -> deep read MLP). Compile-time
// trip count so loads batch. STRIDE is a multiple of 128 float4s, so a
// thread's column quad (g & 127) is loop-invariant.
// NOTE: loads are NORMAL (not non-temporal): they must populate L3 so the
// norm pass re-reads X L3-warm (verified round 2: FETCH 272 MiB for two
// X reads -> second read ~fully L3-served).
#define ST_NBLK   1024
#define ST_THR    512
#define ST_STRIDE (ST_NBLK * ST_THR)          // 524288 float4s
#define ST_ITERS  (TOTAL4 / ST_STRIDE)        // 32, exact

__global__ __launch_bounds__(ST_THR)
void bn_stats_kernel(const v4f* __restrict__ X, float* __restrict__ partial) {
    const int t = threadIdx.x;
    const int g = blockIdx.x * ST_THR + t;

    v4f s = (v4f)0.0f;
    v4f q = (v4f)0.0f;

    #pragma unroll 8
    for (int k = 0; k < ST_ITERS; ++k) {
        v4f x = X[g + k * ST_STRIDE];
        s += x;
        q += x * x;
    }

    __shared__ v4f ls[ST_THR];
    __shared__ v4f lq[ST_THR];
    ls[t] = s;
    lq[t] = q;
    __syncthreads();

    if (t < 256) {
        ls[t] += ls[t + 256];
        lq[t] += lq[t + 256];
    }
    __syncthreads();
    if (t < 128) {
        v4f sv = ls[t] + ls[t + 128];
        v4f qv = lq[t] + lq[t + 128];
        // layout per block: sum[512] then sumsq[512]
        float* dst = partial + (size_t)blockIdx.x * 1024;
        *(v4f*)(dst + 4 * t)       = sv;
        *(v4f*)(dst + 512 + 4 * t) = qv;
    }
}

// ---------------- Pass 1b: reduce partials -> scale/bias ----------------
// One block per column QUAD (128 blocks), v4f loads throughout.
// sb layout: scale[512] then bias[512].
__global__ __launch_bounds__(256)
void bn_finalize_kernel(const float* __restrict__ partial,
                        const float* __restrict__ gamma,
                        const float* __restrict__ beta,
                        float* __restrict__ sb, int B) {
    const int qd = blockIdx.x;   // 0..127
    const int t  = threadIdx.x;

    v4f s = (v4f)0.0f, q = (v4f)0.0f;
    for (int b = t; b < B; b += 256) {
        const float* src = partial + (size_t)b * 1024;
        s += *(const v4f*)(src + 4 * qd);
        q += *(const v4f*)(src + 512 + 4 * qd);
    }

    __shared__ v4f ls[256];
    __shared__ v4f lq[256];
    ls[t] = s;
    lq[t] = q;
    __syncthreads();
    for (int off = 128; off > 0; off >>= 1) {
        if (t < off) { ls[t] += ls[t + off]; lq[t] += lq[t + off]; }
        __syncthreads();
    }

    if (t == 0) {
        const float invN = 1.0f / (float)N_ROWS;
        v4f sv = ls[0], qv = lq[0];
        v4f mean = sv * invN;
        v4f var  = qv * invN - mean * mean;   // no epsilon, per reference
        v4f inv;
        inv.x = rsqrtf(var.x);
        inv.y = rsqrtf(var.y);
        inv.z = rsqrtf(var.z);
        inv.w = rsqrtf(var.w);
        v4f g4 = *(const v4f*)(gamma + 4 * qd);
        v4f b4 = *(const v4f*)(beta  + 4 * qd);
        v4f sc = g4 * inv;
        v4f bi = b4 - mean * sc;
        *(v4f*)(sb + 4 * qd)       = sc;
        *(v4f*)(sb + 512 + 4 * qd) = bi;
    }
}

// ---------------- Pass 2: Y = X*scale + bias ----------------
// 8192 blocks x 256 threads to saturate store BW. X re-read is L3-warm
// (normal loads); Y stores are non-temporal: Y is never re-read, and
// skipping allocation keeps X resident in L3 (X == 256 MiB == L3 size).
#define NM_NBLK   8192
#define NM_THR    256
#define NM_STRIDE (NM_NBLK * NM_THR)          // 2097152 float4s
#define NM_ITERS  (TOTAL4 / NM_STRIDE)        // 8, exact

__global__ __launch_bounds__(NM_THR)
void bn_norm_kernel(const v4f* __restrict__ X,
                    v4f* __restrict__ Y,
                    const float* __restrict__ sb) {
    const int g = blockIdx.x * NM_THR + threadIdx.x;
    const int c = (g & 127) * 4;

    const v4f sc = *(const v4f*)(sb + c);
    const v4f bi = *(const v4f*)(sb + 512 + c);

    #pragma unroll 8
    for (int k = 0; k < NM_ITERS; ++k) {
        v4f x = X[g + k * NM_STRIDE];
        __builtin_nontemporal_store(x * sc + bi, &Y[g + k * NM_STRIDE]);
    }
}

extern "C" void kernel_launch(void* const* d_in, const int* in_sizes, int n_in,
                              void* d_out, int out_size, void* d_ws, size_t ws_size,
                              hipStream_t stream) {
    const float* X     = (const float*)d_in[0];
    const float* gamma = (const float*)d_in[1];
    const float* beta  = (const float*)d_in[2];
    float* Y  = (float*)d_out;
    float* ws = (float*)d_ws;

    // partials: ST_NBLK * 1024 floats (4 MiB) + 4 KiB scale/bias.
    const size_t need = ((size_t)ST_NBLK * 1024 + 1024) * sizeof(float);
    float* partial = ws;
    float* sb      = ws + (size_t)ST_NBLK * 1024;

    if (ws_size >= need) {
        bn_stats_kernel<<<ST_NBLK, ST_THR, 0, stream>>>((const v4f*)X, partial);
        bn_finalize_kernel<<<128, 256, 0, stream>>>(partial, gamma, beta, sb, ST_NBLK);
        bn_norm_kernel<<<NM_NBLK, NM_THR, 0, stream>>>((const v4f*)X, (v4f*)Y, sb);
    }
    // (ws_size is always >= 4 MiB + 4 KiB in this harness; no fallback needed)
}